// Round 7
// baseline (315.072 us; speedup 1.0000x reference)
//
#include <hip/hip_runtime.h>

typedef __attribute__((ext_vector_type(8))) short bf16x8;
typedef __attribute__((ext_vector_type(4))) float f32x4;

constexpr int kB = 2, kN = 4096, kC = 512, kNH = 8, kHD = 64;
constexpr int kBN = kB * kN;                 // 8192
constexpr int kWElems = 262144;              // 512*512
constexpr int kWAll = 6 * kWElems;           // 6 weight matrices
constexpr int kWExtra = 3584;                // dwk(1536) + dwb(512) + dwkT(1536)
constexpr float kQScale = 0.1803368801f;     // (1/8) * log2(e)

__device__ __forceinline__ short f2bf(float f) {
  union { float f; unsigned u; } v; v.f = f;
  unsigned r = v.u + 0x7fffu + ((v.u >> 16) & 1u);
  return (short)(r >> 16);
}
__device__ __forceinline__ float bf2f(short s) {
  union { unsigned u; float f; } v; v.u = ((unsigned)(unsigned short)s) << 16;
  return v.f;
}
__device__ __forceinline__ float exp2_(float x) {
#if __has_builtin(__builtin_amdgcn_exp2f)
  return __builtin_amdgcn_exp2f(x);
#else
  return exp2f(x);
#endif
}

__device__ __forceinline__ bf16x8 ld8(const short* p) { return *(const bf16x8*)p; }
__device__ __forceinline__ bf16x8 ld8(const float* p) {
  float4 a = *(const float4*)p;
  float4 b = *(const float4*)(p + 4);
  bf16x8 r;
  r[0] = f2bf(a.x); r[1] = f2bf(a.y); r[2] = f2bf(a.z); r[3] = f2bf(a.w);
  r[4] = f2bf(b.x); r[5] = f2bf(b.y); r[6] = f2bf(b.z); r[7] = f2bf(b.w);
  return r;
}
__device__ __forceinline__ void stf(short* p, float v) { *p = f2bf(v); }
__device__ __forceinline__ void stf(float* p, float v) { *p = v; }

// async 16B global->LDS (LDS dest wave-uniform base + 16*lane).
__device__ __forceinline__ void gload_lds16(const void* g, void* l) {
  __builtin_amdgcn_global_load_lds(
      (const __attribute__((address_space(1))) void*)g,
      (__attribute__((address_space(3))) void*)l, 16, 0, 0);
}

// K0: classify input dtype on-device.
__global__ void detect_dtype(const unsigned* __restrict__ x, int* __restrict__ flag) {
  const int lane = threadIdx.x & 63;
  unsigned w = x[lane];
  int e = (int)((w >> 7) & 0xffu);
  bool bf = (e >= 100 && e <= 140);
  unsigned long long m = __ballot(bf);
  if (lane == 0) *flag = (__popcll(m) >= 32) ? 1 : 0;
}

// K0b: weights -> bf16: [Wq,Wk,Wv,Wc,Wa,Wco | dwk 1536 | dwb 512 | dwkT 3x512]
__global__ __launch_bounds__(256) void convert_weights(
    const void* Wq, const void* Wk, const void* Wv, const void* Wc,
    const void* Wa, const void* Wco, const void* dwk, const void* dwb,
    const int* __restrict__ flag, short* __restrict__ dst) {
  const int gtid = blockIdx.x * 256 + threadIdx.x;
  const bool bf = (*flag != 0);
  if (gtid < kWAll / 8) {
    const int e = gtid * 8;
    const int t = e >> 18, off = e & (kWElems - 1);
    const void* src = (t == 0) ? Wq : (t == 1) ? Wk : (t == 2) ? Wv
                    : (t == 3) ? Wc : (t == 4) ? Wa : Wco;
    bf16x8 v = bf ? ld8((const short*)src + off) : ld8((const float*)src + off);
    *(bf16x8*)(dst + e) = v;
  } else {
    const int eoff = gtid - kWAll / 8;
    if (eoff < 1536) {        // dwk copy
      dst[kWAll + eoff] = bf ? ((const short*)dwk)[eoff]
                             : f2bf(((const float*)dwk)[eoff]);
    } else if (eoff < 2048) { // dwb copy
      const int i = eoff - 1536;
      dst[kWAll + 1536 + i] = bf ? ((const short*)dwb)[i]
                                 : f2bf(((const float*)dwb)[i]);
    } else if (eoff < 2048 + 1536) {  // dwkT[tap][c] = dwk[c*3+tap]
      const int t2 = eoff - 2048;
      const int tap = t2 >> 9, c = t2 & 511;
      dst[kWAll + 2048 + t2] = bf ? ((const short*)dwk)[c * 3 + tap]
                                  : f2bf(((const float*)dwk)[c * 3 + tap]);
    }
  }
}

// K0c: convert x to bf16 (8 elems/thread).
__global__ __launch_bounds__(256) void convert_x(
    const void* x, const int* __restrict__ flag, short* __restrict__ xb) {
  const int i = (blockIdx.x * 256 + threadIdx.x) * 8;
  bf16x8 v = (*flag) ? ld8((const short*)x + i) : ld8((const float*)x + i);
  *(bf16x8*)(xb + i) = v;
}

// K1: fused input projection GEMM [8192x512] x [2048x512]^T (m97 structure).
__global__ __launch_bounds__(256, 3) void proj_gemm(
    const short* __restrict__ xb, const short* __restrict__ wb,
    short* __restrict__ q, short* __restrict__ k, short* __restrict__ vT,
    short* __restrict__ ci) {
  __shared__ __align__(16) short As[128 * 32];
  __shared__ __align__(16) short Bs[128 * 32];
  const int t = threadIdx.x;
  const int wave = t >> 6, lane = t & 63;
  const int row = lane & 15, quad = lane >> 4;
  const int bn = blockIdx.x & 15;
  const int bm = blockIdx.x >> 4;
  const int m0 = bm * 128, n0 = bn * 128;
  const int wm = wave & 1, wn = wave >> 1;
  const int srow = lane >> 2, schunk = lane & 3;

  f32x4 acc[4][4];
#pragma unroll
  for (int mi = 0; mi < 4; ++mi)
#pragma unroll
    for (int ni = 0; ni < 4; ++ni)
#pragma unroll
      for (int r = 0; r < 4; ++r) acc[mi][ni][r] = 0.0f;

  for (int k0 = 0; k0 < kC; k0 += 32) {
    const short* ga = xb + (size_t)(m0 + wave * 32 + srow) * kC + k0 + schunk * 8;
    const short* gb = wb + (size_t)(n0 + wave * 32 + srow) * kC + k0 + schunk * 8;
    gload_lds16(ga,            &As[(wave * 32) * 32]);
    gload_lds16(ga + 16 * kC,  &As[(wave * 32 + 16) * 32]);
    gload_lds16(gb,            &Bs[(wave * 32) * 32]);
    gload_lds16(gb + 16 * kC,  &Bs[(wave * 32 + 16) * 32]);
    __syncthreads();

    bf16x8 af[4], bfr[4];
#pragma unroll
    for (int mi = 0; mi < 4; ++mi)
      af[mi] = *(const bf16x8*)(&As[(wm * 64 + mi * 16 + row) * 32 + quad * 8]);
#pragma unroll
    for (int ni = 0; ni < 4; ++ni)
      bfr[ni] = *(const bf16x8*)(&Bs[(wn * 64 + ni * 16 + row) * 32 + quad * 8]);
#pragma unroll
    for (int mi = 0; mi < 4; ++mi)
#pragma unroll
      for (int ni = 0; ni < 4; ++ni)
        acc[mi][ni] = __builtin_amdgcn_mfma_f32_16x16x32_bf16(
            af[mi], bfr[ni], acc[mi][ni], 0, 0, 0);
    __syncthreads();
  }

  const int gc0 = n0 + wn * 64;
  const int mat = gc0 >> 9;
  const float scale = (mat == 0) ? kQScale : 1.0f;
#pragma unroll
  for (int mi = 0; mi < 4; ++mi) {
#pragma unroll
    for (int ni = 0; ni < 4; ++ni) {
#pragma unroll
      for (int r = 0; r < 4; ++r) {
        const int gm = m0 + wm * 64 + mi * 16 + quad * 4 + r;
        const int c_ = ((gc0 + ni * 16) & 511) + row;
        const int b_ = gm >> 12;
        const int n_ = gm & (kN - 1);
        const short bv = f2bf(acc[mi][ni][r] * scale);
        if (mat == 3) {
          ci[(b_ * kN + n_) * kC + c_] = bv;
        } else {
          const int h = c_ >> 6, d = c_ & 63;
          const int bh = b_ * kNH + h;
          if (mat == 0)      q[(bh * kN + n_) * kHD + d] = bv;
          else if (mat == 1) k[(bh * kN + n_) * kHD + d] = bv;
          else               vT[(bh * kHD + d) * kN + n_] = bv;
        }
      }
    }
  }
}

// K2: depthwise conv, vectorized bf16x8 (uses dwkT + dwb from wb).
__global__ __launch_bounds__(256) void dwconv(
    const short* __restrict__ ci, const short* __restrict__ wb,
    short* __restrict__ cb) {
  const int e0 = (blockIdx.x * 256 + threadIdx.x) * 8;
  const int c0 = e0 & (kC - 1);
  const int bn = e0 >> 9;
  const int n_ = bn & (kN - 1);
  bf16x8 xc = ld8(ci + e0);
  bf16x8 xm, xp;
  if (n_ > 0) xm = ld8(ci + e0 - kC);
  else
#pragma unroll
    for (int i = 0; i < 8; ++i) xm[i] = 0;
  if (n_ < kN - 1) xp = ld8(ci + e0 + kC);
  else
#pragma unroll
    for (int i = 0; i < 8; ++i) xp[i] = 0;
  bf16x8 w0 = ld8(wb + kWAll + 2048 + c0);
  bf16x8 w1 = ld8(wb + kWAll + 2048 + 512 + c0);
  bf16x8 w2 = ld8(wb + kWAll + 2048 + 1024 + c0);
  bf16x8 bi = ld8(wb + kWAll + 1536 + c0);
  bf16x8 o;
#pragma unroll
  for (int i = 0; i < 8; ++i) {
    float a = bf2f(bi[i]) + bf2f(xm[i]) * bf2f(w0[i]) +
              bf2f(xc[i]) * bf2f(w1[i]) + bf2f(xp[i]) * bf2f(w2[i]);
    o[i] = f2bf(a);
  }
  *(bf16x8*)(cb + e0) = o;
}

// ---------------------------------------------------------------------------
// K3: flash attention v3.
//  - K via LDS, double-buffered, chunked layout [8 d-chunks][64+pad rows][8]
//    (conflict-free writes AND reads). Staged through regs cooperatively.
//  - V NEVER touches LDS: per-wave global->reg prefetch (depth 1, 8 b128);
//    rides the TA/L1 pipe in parallel with the LDS pipe.
//  - P per-wave LDS, chunked [8 k-chunks][16][8] unpadded (conflict-free).
//  - ONE barrier per kt (only Kb is cross-wave).
//  - Fixed-reference softmax; l accumulated per-lane, cross-lane reduced ONCE
//    after the loop (no in-loop shuffles).
// ---------------------------------------------------------------------------
__global__ __launch_bounds__(256, 2) void attn_flash(
    const short* __restrict__ q, const short* __restrict__ k,
    const short* __restrict__ vT, short* __restrict__ attn) {
  __shared__ __align__(16) short Kb[2][8 * 520];      // 2 x 8320 B
  __shared__ __align__(16) short Pb[4][2][8 * 128];   // 4 x 4096 B
  const int t = threadIdx.x;
  const int wave = t >> 6;
  const int lane = t & 63;
  const int row = lane & 15;
  const int quad = lane >> 4;

  const int slot = blockIdx.x & 7;
  const int inner = blockIdx.x >> 3;
  const int bh = slot * 2 + (inner & 1);
  const int q0 = (inner >> 1) * 128 + wave * 32;

  const short* qbase = q + (bh * kN + q0) * kHD;
  const short* kbase = k + bh * kN * kHD;
  const short* vbase = vT + bh * kHD * kN;

  // Q fragments (B-operand), 2 groups of 16 q-rows.
  bf16x8 qb[2][2];
#pragma unroll
  for (int g = 0; g < 2; ++g) {
    qb[g][0] = *(const bf16x8*)(qbase + (g * 16 + row) * kHD + quad * 8);
    qb[g][1] = *(const bf16x8*)(qbase + (g * 16 + row) * kHD + 32 + quad * 8);
  }

  f32x4 o[2][4];
#pragma unroll
  for (int g = 0; g < 2; ++g)
#pragma unroll
    for (int j = 0; j < 4; ++j)
#pragma unroll
      for (int r = 0; r < 4; ++r) o[g][j][r] = 0.0f;
  float l_[2] = {0.0f, 0.0f};

  // K staging: thread handles global 16B chunks i0,i1; row=g>>3, dchunk=g&7.
  const int i0 = t, i1 = t + 256;
  const int kr0 = i0 >> 3, kd0 = i0 & 7;
  const int kr1 = i1 >> 3, kd1 = i1 & 7;
  const short* kptr0 = kbase + i0 * 8;
  const short* kptr1 = kbase + i1 * 8;

  // V row pointers (per-lane): vrow[jd] -> V[d = jd*16+row] at current kt.
  const short* vrow[4];
#pragma unroll
  for (int jd = 0; jd < 4; ++jd)
    vrow[jd] = vbase + (jd * 16 + row) * kN + quad * 8;

  // prologue: K0 -> Kb[0], V0 -> vf regs.
  {
    bf16x8 ka = *(const bf16x8*)kptr0;
    bf16x8 kb2 = *(const bf16x8*)kptr1;
    *(bf16x8*)(&Kb[0][kd0 * 520 + kr0 * 8]) = ka;
    *(bf16x8*)(&Kb[0][kd1 * 520 + kr1 * 8]) = kb2;
    kptr0 += 4096; kptr1 += 4096;
  }
  bf16x8 vf[8];
#pragma unroll
  for (int j2 = 0; j2 < 2; ++j2)
#pragma unroll
    for (int jd = 0; jd < 4; ++jd)
      vf[j2 * 4 + jd] = *(const bf16x8*)(vrow[jd] + j2 * 32);
#pragma unroll
  for (int jd = 0; jd < 4; ++jd) vrow[jd] += 64;
  __syncthreads();

  constexpr int NT = kN / 64;
#pragma unroll 2
  for (int kt = 0; kt < NT; ++kt) {
    const int cur = kt & 1;
    const bool more = (kt < NT - 1);
    // issue K(t+1), V(t+1) global loads
    bf16x8 kn0, kn1, vfn[8];
    if (more) {
      kn0 = *(const bf16x8*)kptr0;
      kn1 = *(const bf16x8*)kptr1;
      kptr0 += 4096; kptr1 += 4096;
#pragma unroll
      for (int j2 = 0; j2 < 2; ++j2)
#pragma unroll
        for (int jd = 0; jd < 4; ++jd)
          vfn[j2 * 4 + jd] = *(const bf16x8*)(vrow[jd] + j2 * 32);
#pragma unroll
      for (int jd = 0; jd < 4; ++jd) vrow[jd] += 64;
    }

    // ---- QK from Kb (chunked): S^T strips for both groups ----
    f32x4 s[2][4];
#pragma unroll
    for (int g = 0; g < 2; ++g)
#pragma unroll
      for (int jk = 0; jk < 4; ++jk)
#pragma unroll
        for (int r = 0; r < 4; ++r) s[g][jk][r] = 0.0f;
#pragma unroll
    for (int jk = 0; jk < 4; ++jk) {
      bf16x8 a0 = *(const bf16x8*)(&Kb[cur][quad * 520 + (jk * 16 + row) * 8]);
      bf16x8 a1 = *(const bf16x8*)(&Kb[cur][(quad + 4) * 520 + (jk * 16 + row) * 8]);
#pragma unroll
      for (int g = 0; g < 2; ++g) {
        s[g][jk] = __builtin_amdgcn_mfma_f32_16x16x32_bf16(a0, qb[g][0], s[g][jk], 0, 0, 0);
        s[g][jk] = __builtin_amdgcn_mfma_f32_16x16x32_bf16(a1, qb[g][1], s[g][jk], 0, 0, 0);
      }
    }

    // ---- softmax (fixed ref, exp2 domain), per-lane l accumulation ----
#pragma unroll
    for (int g = 0; g < 2; ++g) {
      float rs = 0.0f;
#pragma unroll
      for (int jk = 0; jk < 4; ++jk)
#pragma unroll
        for (int r = 0; r < 4; ++r) {
          float p = exp2_(s[g][jk][r]);
          s[g][jk][r] = p;
          rs += p;
        }
      l_[g] += rs;
      // P writes, chunked: k = jk*16 + quad*4 + r -> chunk jk*2+(quad>>1)
      short* Pw = &Pb[wave][g][0];
#pragma unroll
      for (int jk = 0; jk < 4; ++jk) {
        short4 pk = make_short4(f2bf(s[g][jk][0]), f2bf(s[g][jk][1]),
                                f2bf(s[g][jk][2]), f2bf(s[g][jk][3]));
        *(short4*)(Pw + (jk * 2 + (quad >> 1)) * 128 + row * 8 + (quad & 1) * 4) = pk;
      }
    }

    // ---- stage K(t+1) into other buffer (pre-barrier) ----
    if (more) {
      *(bf16x8*)(&Kb[1 - cur][kd0 * 520 + kr0 * 8]) = kn0;
      *(bf16x8*)(&Kb[1 - cur][kd1 * 520 + kr1 * 8]) = kn1;
    }
    __syncthreads();

    // ---- PV: P from per-wave LDS (A-frag), V from regs ----
#pragma unroll
    for (int j2 = 0; j2 < 2; ++j2) {
      bf16x8 pa[2];
#pragma unroll
      for (int g = 0; g < 2; ++g)
        pa[g] = *(const bf16x8*)(&Pb[wave][g][(j2 * 4 + quad) * 128 + row * 8]);
#pragma unroll
      for (int jd = 0; jd < 4; ++jd) {
#pragma unroll
        for (int g = 0; g < 2; ++g)
          o[g][jd] = __builtin_amdgcn_mfma_f32_16x16x32_bf16(
              pa[g], vf[j2 * 4 + jd], o[g][jd], 0, 0, 0);
      }
    }

    // rotate V prefetch
    if (more) {
#pragma unroll
      for (int i = 0; i < 8; ++i) vf[i] = vfn[i];
    }
  }

  // ---- cross-lane l reduction (once) + finalize ----
  const int b_ = bh >> 3, h = bh & 7;
#pragma unroll
  for (int g = 0; g < 2; ++g) {
    float lt = l_[g];
    lt += __shfl_xor(lt, 16);
    lt += __shfl_xor(lt, 32);
    float linv[4];
#pragma unroll
    for (int r = 0; r < 4; ++r) linv[r] = 1.0f / __shfl(lt, quad * 4 + r);
#pragma unroll
    for (int jd = 0; jd < 4; ++jd)
#pragma unroll
      for (int r = 0; r < 4; ++r) {
        const int n_ = q0 + g * 16 + quad * 4 + r;
        const int c_ = h * kHD + jd * 16 + row;
        attn[(b_ * kN + n_) * kC + c_] = f2bf(o[g][jd][r] * linv[r]);
      }
  }
}

// K4: out = [attn|cb] @ [Wa|Wo]^T, single GEMM M=8192 N=512 K=1024.
template <typename TO>
__device__ __forceinline__ void out_body(
    const short* __restrict__ attn, const short* __restrict__ cb,
    const short* __restrict__ wb, TO* __restrict__ out) {
  __shared__ __align__(16) short As[128 * 32];
  __shared__ __align__(16) short Bs[64 * 32];
  const int t = threadIdx.x;
  const int wave = t >> 6, lane = t & 63;
  const int row = lane & 15, quad = lane >> 4;
  const int bn = blockIdx.x & 7;
  const int bm = blockIdx.x >> 3;
  const int m0 = bm * 128, n0 = bn * 64;
  const int wm = wave & 1, wn = wave >> 1;
  const int srow = lane >> 2, schunk = lane & 3;

  f32x4 acc[4][2];
#pragma unroll
  for (int mi = 0; mi < 4; ++mi)
#pragma unroll
    for (int ni = 0; ni < 2; ++ni)
#pragma unroll
      for (int r = 0; r < 4; ++r) acc[mi][ni][r] = 0.0f;

  const short* Wa = wb + 4 * kWElems;
  const short* Wo = wb + 5 * kWElems;

  for (int k0 = 0; k0 < 1024; k0 += 32) {
    const short* Asrc = (k0 < 512) ? attn : cb;
    const short* Bsrc = (k0 < 512) ? Wa : Wo;
    const int ka = k0 & 511;
    const short* ga = Asrc + (size_t)(m0 + wave * 32 + srow) * kC + ka + schunk * 8;
    gload_lds16(ga,            &As[(wave * 32) * 32]);
    gload_lds16(ga + 16 * kC,  &As[(wave * 32 + 16) * 32]);
    const short* gb = Bsrc + (size_t)(n0 + wave * 16 + srow) * kC + ka + schunk * 8;
    gload_lds16(gb, &Bs[(wave * 16) * 32]);
    __syncthreads();

    bf16x8 af[4], bfr[2];
#pragma unroll
    for (int mi = 0; mi < 4; ++mi)
      af[mi] = *(const bf16x8*)(&As[(wm * 64 + mi * 16 + row) * 32 + quad * 8]);
#pragma unroll
    for (int ni = 0; ni < 2; ++ni)
      bfr[ni] = *(const bf16x8*)(&Bs[(wn * 32 + ni * 16 + row) * 32 + quad * 8]);
#pragma unroll
    for (int mi = 0; mi < 4; ++mi)
#pragma unroll
      for (int ni = 0; ni < 2; ++ni)
        acc[mi][ni] = __builtin_amdgcn_mfma_f32_16x16x32_bf16(
            af[mi], bfr[ni], acc[mi][ni], 0, 0, 0);
    __syncthreads();
  }

#pragma unroll
  for (int mi = 0; mi < 4; ++mi)
#pragma unroll
    for (int ni = 0; ni < 2; ++ni)
#pragma unroll
      for (int r = 0; r < 4; ++r) {
        const int gm = m0 + wm * 64 + mi * 16 + quad * 4 + r;
        const int gc = n0 + wn * 32 + ni * 16 + row;
        stf(out + (size_t)gm * kC + gc, acc[mi][ni][r]);
      }
}

__global__ __launch_bounds__(256, 4) void out_gemm(
    const short* __restrict__ attn, const short* __restrict__ cb,
    const short* __restrict__ wb, const int* __restrict__ flag, void* out) {
  if (*flag)
    out_body<short>(attn, cb, wb, (short*)out);
  else
    out_body<float>(attn, cb, wb, (float*)out);
}

extern "C" void kernel_launch(void* const* d_in, const int* in_sizes, int n_in,
                              void* d_out, int out_size, void* d_ws, size_t ws_size,
                              hipStream_t stream) {
  const void* x   = d_in[0];
  const void* Wq  = d_in[1];
  const void* Wk  = d_in[2];
  const void* Wv  = d_in[3];
  const void* Wa  = d_in[4];
  const void* Wc  = d_in[5];
  const void* dwk = d_in[6];
  const void* dwb = d_in[7];
  const void* Wco = d_in[8];

  short* ws = (short*)d_ws;
  const size_t E = (size_t)kBN * kC;
  int*   flag = (int*)ws;
  short* wb   = ws + 256;
  short* q    = wb + kWAll + kWExtra;
  short* k    = q + E;
  short* vT   = k + E;
  short* ci   = vT + E;
  short* cb   = ci + E;
  short* attn = ci;   // attn overwrites ci (consumed by dwconv first)
  short* xb   = cb;   // consumed by proj_gemm before dwconv writes cb

  detect_dtype<<<1, 64, 0, stream>>>((const unsigned*)x, flag);
  convert_weights<<<(kWAll / 8 + kWExtra + 255) / 256, 256, 0, stream>>>(
      Wq, Wk, Wv, Wc, Wa, Wco, dwk, dwb, flag, wb);
  convert_x<<<kBN * kC / (256 * 8), 256, 0, stream>>>(x, flag, xb);
  proj_gemm<<<1024, 256, 0, stream>>>(xb, wb, q, k, vT, ci);
  dwconv<<<(kBN * kC) / (256 * 8), 256, 0, stream>>>(ci, wb, cb);
  attn_flash<<<512, 256, 0, stream>>>(q, k, vT, attn);
  out_gemm<<<512, 256, 0, stream>>>(attn, cb, wb, flag, d_out);
}

// Round 8
// 267.065 us; speedup vs baseline: 1.1798x; 1.1798x over previous
//
#include <hip/hip_runtime.h>

typedef __attribute__((ext_vector_type(8))) short bf16x8;
typedef __attribute__((ext_vector_type(4))) short bf16x4;
typedef __attribute__((ext_vector_type(4))) float f32x4;

constexpr int kB = 2, kN = 4096, kC = 512, kNH = 8, kHD = 64;
constexpr int kBN = kB * kN;                 // 8192
constexpr int kWElems = 262144;              // 512*512
constexpr int kWAll = 6 * kWElems;           // 6 weight matrices
constexpr int kWExtra = 3584;                // dwk(1536) + dwb(512) + dwkT(1536)
constexpr float kQScale = 0.1803368801f;     // (1/8) * log2(e)

__device__ __forceinline__ short f2bf(float f) {
  union { float f; unsigned u; } v; v.f = f;
  unsigned r = v.u + 0x7fffu + ((v.u >> 16) & 1u);
  return (short)(r >> 16);
}
__device__ __forceinline__ float bf2f(short s) {
  union { unsigned u; float f; } v; v.u = ((unsigned)(unsigned short)s) << 16;
  return v.f;
}
__device__ __forceinline__ float exp2_(float x) {
#if __has_builtin(__builtin_amdgcn_exp2f)
  return __builtin_amdgcn_exp2f(x);
#else
  return exp2f(x);
#endif
}

__device__ __forceinline__ bf16x8 ld8(const short* p) { return *(const bf16x8*)p; }
__device__ __forceinline__ bf16x8 ld8(const float* p) {
  float4 a = *(const float4*)p;
  float4 b = *(const float4*)(p + 4);
  bf16x8 r;
  r[0] = f2bf(a.x); r[1] = f2bf(a.y); r[2] = f2bf(a.z); r[3] = f2bf(a.w);
  r[4] = f2bf(b.x); r[5] = f2bf(b.y); r[6] = f2bf(b.z); r[7] = f2bf(b.w);
  return r;
}
__device__ __forceinline__ void stf(short* p, float v) { *p = f2bf(v); }
__device__ __forceinline__ void stf(float* p, float v) { *p = v; }

// async 16B global->LDS (LDS dest wave-uniform base + 16*lane).
__device__ __forceinline__ void gload_lds16(const void* g, void* l) {
  __builtin_amdgcn_global_load_lds(
      (const __attribute__((address_space(1))) void*)g,
      (__attribute__((address_space(3))) void*)l, 16, 0, 0);
}

// K0: classify input dtype on-device.
__global__ void detect_dtype(const unsigned* __restrict__ x, int* __restrict__ flag) {
  const int lane = threadIdx.x & 63;
  unsigned w = x[lane];
  int e = (int)((w >> 7) & 0xffu);
  bool bf = (e >= 100 && e <= 140);
  unsigned long long m = __ballot(bf);
  if (lane == 0) *flag = (__popcll(m) >= 32) ? 1 : 0;
}

// K0b: weights -> bf16: [Wq,Wk,Wv,Wc,Wa,Wco | dwk 1536 | dwb 512 | dwkT 3x512]
__global__ __launch_bounds__(256) void convert_weights(
    const void* Wq, const void* Wk, const void* Wv, const void* Wc,
    const void* Wa, const void* Wco, const void* dwk, const void* dwb,
    const int* __restrict__ flag, short* __restrict__ dst) {
  const int gtid = blockIdx.x * 256 + threadIdx.x;
  const bool bf = (*flag != 0);
  if (gtid < kWAll / 8) {
    const int e = gtid * 8;
    const int t = e >> 18, off = e & (kWElems - 1);
    const void* src = (t == 0) ? Wq : (t == 1) ? Wk : (t == 2) ? Wv
                    : (t == 3) ? Wc : (t == 4) ? Wa : Wco;
    bf16x8 v = bf ? ld8((const short*)src + off) : ld8((const float*)src + off);
    *(bf16x8*)(dst + e) = v;
  } else {
    const int eoff = gtid - kWAll / 8;
    if (eoff < 1536) {        // dwk copy
      dst[kWAll + eoff] = bf ? ((const short*)dwk)[eoff]
                             : f2bf(((const float*)dwk)[eoff]);
    } else if (eoff < 2048) { // dwb copy
      const int i = eoff - 1536;
      dst[kWAll + 1536 + i] = bf ? ((const short*)dwb)[i]
                                 : f2bf(((const float*)dwb)[i]);
    } else if (eoff < 2048 + 1536) {  // dwkT[tap][c] = dwk[c*3+tap]
      const int t2 = eoff - 2048;
      const int tap = t2 >> 9, c = t2 & 511;
      dst[kWAll + 2048 + t2] = bf ? ((const short*)dwk)[c * 3 + tap]
                                  : f2bf(((const float*)dwk)[c * 3 + tap]);
    }
  }
}

// K0c: convert x to bf16 (8 elems/thread).
__global__ __launch_bounds__(256) void convert_x(
    const void* x, const int* __restrict__ flag, short* __restrict__ xb) {
  const int i = (blockIdx.x * 256 + threadIdx.x) * 8;
  bf16x8 v = (*flag) ? ld8((const short*)x + i) : ld8((const float*)x + i);
  *(bf16x8*)(xb + i) = v;
}

// K1: fused input projection GEMM [8192x512] x [2048x512]^T (m97 structure).
__global__ __launch_bounds__(256, 3) void proj_gemm(
    const short* __restrict__ xb, const short* __restrict__ wb,
    short* __restrict__ q, short* __restrict__ k, short* __restrict__ vT,
    short* __restrict__ ci) {
  __shared__ __align__(16) short As[128 * 32];
  __shared__ __align__(16) short Bs[128 * 32];
  const int t = threadIdx.x;
  const int wave = t >> 6, lane = t & 63;
  const int row = lane & 15, quad = lane >> 4;
  const int bn = blockIdx.x & 15;
  const int bm = blockIdx.x >> 4;
  const int m0 = bm * 128, n0 = bn * 128;
  const int wm = wave & 1, wn = wave >> 1;
  const int srow = lane >> 2, schunk = lane & 3;

  f32x4 acc[4][4];
#pragma unroll
  for (int mi = 0; mi < 4; ++mi)
#pragma unroll
    for (int ni = 0; ni < 4; ++ni)
#pragma unroll
      for (int r = 0; r < 4; ++r) acc[mi][ni][r] = 0.0f;

  for (int k0 = 0; k0 < kC; k0 += 32) {
    const short* ga = xb + (size_t)(m0 + wave * 32 + srow) * kC + k0 + schunk * 8;
    const short* gb = wb + (size_t)(n0 + wave * 32 + srow) * kC + k0 + schunk * 8;
    gload_lds16(ga,            &As[(wave * 32) * 32]);
    gload_lds16(ga + 16 * kC,  &As[(wave * 32 + 16) * 32]);
    gload_lds16(gb,            &Bs[(wave * 32) * 32]);
    gload_lds16(gb + 16 * kC,  &Bs[(wave * 32 + 16) * 32]);
    __syncthreads();

    bf16x8 af[4], bfr[4];
#pragma unroll
    for (int mi = 0; mi < 4; ++mi)
      af[mi] = *(const bf16x8*)(&As[(wm * 64 + mi * 16 + row) * 32 + quad * 8]);
#pragma unroll
    for (int ni = 0; ni < 4; ++ni)
      bfr[ni] = *(const bf16x8*)(&Bs[(wn * 64 + ni * 16 + row) * 32 + quad * 8]);
#pragma unroll
    for (int mi = 0; mi < 4; ++mi)
#pragma unroll
      for (int ni = 0; ni < 4; ++ni)
        acc[mi][ni] = __builtin_amdgcn_mfma_f32_16x16x32_bf16(
            af[mi], bfr[ni], acc[mi][ni], 0, 0, 0);
    __syncthreads();
  }

  const int gc0 = n0 + wn * 64;
  const int mat = gc0 >> 9;
  const float scale = (mat == 0) ? kQScale : 1.0f;
#pragma unroll
  for (int mi = 0; mi < 4; ++mi) {
#pragma unroll
    for (int ni = 0; ni < 4; ++ni) {
#pragma unroll
      for (int r = 0; r < 4; ++r) {
        const int gm = m0 + wm * 64 + mi * 16 + quad * 4 + r;
        const int c_ = ((gc0 + ni * 16) & 511) + row;
        const int b_ = gm >> 12;
        const int n_ = gm & (kN - 1);
        const short bv = f2bf(acc[mi][ni][r] * scale);
        if (mat == 3) {
          ci[(b_ * kN + n_) * kC + c_] = bv;
        } else {
          const int h = c_ >> 6, d = c_ & 63;
          const int bh = b_ * kNH + h;
          if (mat == 0)      q[(bh * kN + n_) * kHD + d] = bv;
          else if (mat == 1) k[(bh * kN + n_) * kHD + d] = bv;
          else               vT[(bh * kHD + d) * kN + n_] = bv;
        }
      }
    }
  }
}

// K2: depthwise conv, vectorized bf16x8 (uses dwkT + dwb from wb).
__global__ __launch_bounds__(256) void dwconv(
    const short* __restrict__ ci, const short* __restrict__ wb,
    short* __restrict__ cb) {
  const int e0 = (blockIdx.x * 256 + threadIdx.x) * 8;
  const int c0 = e0 & (kC - 1);
  const int bn = e0 >> 9;
  const int n_ = bn & (kN - 1);
  bf16x8 xc = ld8(ci + e0);
  bf16x8 xm, xp;
  if (n_ > 0) xm = ld8(ci + e0 - kC);
  else
#pragma unroll
    for (int i = 0; i < 8; ++i) xm[i] = 0;
  if (n_ < kN - 1) xp = ld8(ci + e0 + kC);
  else
#pragma unroll
    for (int i = 0; i < 8; ++i) xp[i] = 0;
  bf16x8 w0 = ld8(wb + kWAll + 2048 + c0);
  bf16x8 w1 = ld8(wb + kWAll + 2048 + 512 + c0);
  bf16x8 w2 = ld8(wb + kWAll + 2048 + 1024 + c0);
  bf16x8 bi = ld8(wb + kWAll + 1536 + c0);
  bf16x8 o;
#pragma unroll
  for (int i = 0; i < 8; ++i) {
    float a = bf2f(bi[i]) + bf2f(xm[i]) * bf2f(w0[i]) +
              bf2f(xc[i]) * bf2f(w1[i]) + bf2f(xp[i]) * bf2f(w2[i]);
    o[i] = f2bf(a);
  }
  *(bf16x8*)(cb + e0) = o;
}

// ---------------------------------------------------------------------------
// K3: flash attention v4 (R6 cooperative structure + zero-LDS P).
//  - K and V cooperatively staged to LDS [64][72] (K double-buffered).
//  - PV computed TRANSPOSED (O^T = V^T-as-A x P^T-as-B) with a permuted
//    contraction index chosen so the P^T B-fragment is the lane's OWN QK
//    output registers -> P never touches LDS (-32KB/block-kt, no P-write
//    bank conflicts). V A-frags = two ds_read_b64 at permuted offsets.
//  - Fixed-reference softmax (exp2 domain); l accumulated per-lane,
//    cross-lane reduced once after the loop; per-lane scalar 1/l.
//  - O^T C-layout epilogue: packed 8B stores, no broadcast shuffles.
// ---------------------------------------------------------------------------
__global__ __launch_bounds__(256, 3) void attn_flash(
    const short* __restrict__ q, const short* __restrict__ k,
    const short* __restrict__ vT, short* __restrict__ attn) {
  __shared__ __align__(16) short Kb[2][64 * 72];   // 18,432 B
  __shared__ __align__(16) short Vb[64 * 72];      //  9,216 B
  const int t = threadIdx.x;
  const int wave = t >> 6;
  const int lane = t & 63;
  const int row = lane & 15;     // q index within 16-group
  const int quad = lane >> 4;

  const int slot = blockIdx.x & 7;
  const int inner = blockIdx.x >> 3;
  const int bh = slot * 2 + (inner & 1);
  const int q0 = (inner >> 1) * 128 + wave * 32;

  const short* qbase = q + (bh * kN + q0) * kHD;
  const short* kbase = k + bh * kN * kHD;
  const short* vbase = vT + bh * kHD * kN;

  // Q fragments (B-operand for QK), 2 groups of 16 q-rows.
  bf16x8 qb[2][2];
#pragma unroll
  for (int g = 0; g < 2; ++g) {
    qb[g][0] = *(const bf16x8*)(qbase + (g * 16 + row) * kHD + quad * 8);
    qb[g][1] = *(const bf16x8*)(qbase + (g * 16 + row) * kHD + 32 + quad * 8);
  }

  f32x4 o[2][4];   // O^T accumulators: o[g][jd][r] = O^T[jd*16+quad*4+r][q=row]
#pragma unroll
  for (int g = 0; g < 2; ++g)
#pragma unroll
    for (int j = 0; j < 4; ++j)
#pragma unroll
      for (int r = 0; r < 4; ++r) o[g][j][r] = 0.0f;
  float l_[2] = {0.0f, 0.0f};

  // cooperative staging geometry: 512 x 16B chunks per 64x64 tile.
  const int i0 = t, i1 = t + 256;
  const int sr0 = i0 >> 3, sc0 = i0 & 7;
  const int sr1 = i1 >> 3, sc1 = i1 & 7;

  { // prologue: K-tile 0
    bf16x8 ka = *(const bf16x8*)(kbase + i0 * 8);
    bf16x8 kb2 = *(const bf16x8*)(kbase + i1 * 8);
    *(bf16x8*)(&Kb[0][sr0 * 72 + sc0 * 8]) = ka;
    *(bf16x8*)(&Kb[0][sr1 * 72 + sc1 * 8]) = kb2;
  }
  __syncthreads();

  for (int kt = 0; kt < kN / 64; ++kt) {
    const int cur = kt & 1;
    // issue cooperative global loads: V(kt), K(kt+1)
    bf16x8 v0 = *(const bf16x8*)(vbase + sr0 * kN + kt * 64 + sc0 * 8);
    bf16x8 v1 = *(const bf16x8*)(vbase + sr1 * kN + kt * 64 + sc1 * 8);
    bf16x8 kn0, kn1;
    if (kt < kN / 64 - 1) {
      kn0 = *(const bf16x8*)(kbase + (kt + 1) * 4096 + i0 * 8);
      kn1 = *(const bf16x8*)(kbase + (kt + 1) * 4096 + i1 * 8);
    }

    // ---- QK from Kb: S^T strips. s[g][jk][r] = S^T[jk*16+quad*4+r][row] ----
    f32x4 s[2][4];
#pragma unroll
    for (int g = 0; g < 2; ++g)
#pragma unroll
      for (int jk = 0; jk < 4; ++jk)
#pragma unroll
        for (int r = 0; r < 4; ++r) s[g][jk][r] = 0.0f;
#pragma unroll
    for (int jk = 0; jk < 4; ++jk) {
      const short* kr = &Kb[cur][(jk * 16 + row) * 72 + quad * 8];
      bf16x8 a0 = *(const bf16x8*)kr;
      bf16x8 a1 = *(const bf16x8*)(kr + 32);
#pragma unroll
      for (int g = 0; g < 2; ++g) {
        s[g][jk] = __builtin_amdgcn_mfma_f32_16x16x32_bf16(a0, qb[g][0], s[g][jk], 0, 0, 0);
        s[g][jk] = __builtin_amdgcn_mfma_f32_16x16x32_bf16(a1, qb[g][1], s[g][jk], 0, 0, 0);
      }
    }

    // ---- softmax (fixed ref, exp2 domain) + in-register P^T B-frags ----
    // pb[g][c][j] = P^T[c*32 + (j>>2)*16 + quad*4 + (j&3)][row]
    bf16x8 pb[2][2];
#pragma unroll
    for (int g = 0; g < 2; ++g) {
      float rs = 0.0f;
#pragma unroll
      for (int jk = 0; jk < 4; ++jk)
#pragma unroll
        for (int r = 0; r < 4; ++r) {
          float p = exp2_(s[g][jk][r]);
          s[g][jk][r] = p;
          rs += p;
        }
      l_[g] += rs;
#pragma unroll
      for (int c = 0; c < 2; ++c)
#pragma unroll
        for (int j = 0; j < 4; ++j) {
          pb[g][c][j]     = f2bf(s[g][2 * c][j]);
          pb[g][c][j + 4] = f2bf(s[g][2 * c + 1][j]);
        }
    }

    // ---- stage V, barrier ----
    *(bf16x8*)(&Vb[sr0 * 72 + sc0 * 8]) = v0;
    *(bf16x8*)(&Vb[sr1 * 72 + sc1 * 8]) = v1;
    __syncthreads();

    // ---- PV (transposed): A = V rows at permuted offsets, B = pb regs ----
#pragma unroll
    for (int jd = 0; jd < 4; ++jd) {
      const short* vb = &Vb[(jd * 16 + row) * 72 + quad * 4];
#pragma unroll
      for (int c = 0; c < 2; ++c) {
        bf16x4 lo = *(const bf16x4*)(vb + c * 32);
        bf16x4 hi = *(const bf16x4*)(vb + c * 32 + 16);
        bf16x8 av = __builtin_shufflevector(lo, hi, 0, 1, 2, 3, 4, 5, 6, 7);
#pragma unroll
        for (int g = 0; g < 2; ++g)
          o[g][jd] = __builtin_amdgcn_mfma_f32_16x16x32_bf16(
              av, pb[g][c], o[g][jd], 0, 0, 0);
      }
    }

    // ---- stage K(kt+1) into the other buffer ----
    if (kt < kN / 64 - 1) {
      *(bf16x8*)(&Kb[1 - cur][sr0 * 72 + sc0 * 8]) = kn0;
      *(bf16x8*)(&Kb[1 - cur][sr1 * 72 + sc1 * 8]) = kn1;
    }
    __syncthreads();
  }

  // ---- finalize: O^T layout -> attn[B][N][C], packed 8B stores ----
  const int b_ = bh >> 3, h = bh & 7;
#pragma unroll
  for (int g = 0; g < 2; ++g) {
    float lt = l_[g];
    lt += __shfl_xor(lt, 16);
    lt += __shfl_xor(lt, 32);
    const float linv = 1.0f / lt;          // l for q = row (per-lane scalar)
    const int n_ = q0 + g * 16 + row;
    short* ob = attn + (b_ * kN + n_) * kC + h * kHD + quad * 4;
#pragma unroll
    for (int jd = 0; jd < 4; ++jd) {
      short4 st = make_short4(f2bf(o[g][jd][0] * linv), f2bf(o[g][jd][1] * linv),
                              f2bf(o[g][jd][2] * linv), f2bf(o[g][jd][3] * linv));
      *(short4*)(ob + jd * 16) = st;
    }
  }
}

// K4: out = [attn|cb] @ [Wa|Wo]^T, single GEMM M=8192 N=512 K=1024.
template <typename TO>
__device__ __forceinline__ void out_body(
    const short* __restrict__ attn, const short* __restrict__ cb,
    const short* __restrict__ wb, TO* __restrict__ out) {
  __shared__ __align__(16) short As[128 * 32];
  __shared__ __align__(16) short Bs[64 * 32];
  const int t = threadIdx.x;
  const int wave = t >> 6, lane = t & 63;
  const int row = lane & 15, quad = lane >> 4;
  const int bn = blockIdx.x & 7;
  const int bm = blockIdx.x >> 3;
  const int m0 = bm * 128, n0 = bn * 64;
  const int wm = wave & 1, wn = wave >> 1;
  const int srow = lane >> 2, schunk = lane & 3;

  f32x4 acc[4][2];
#pragma unroll
  for (int mi = 0; mi < 4; ++mi)
#pragma unroll
    for (int ni = 0; ni < 2; ++ni)
#pragma unroll
      for (int r = 0; r < 4; ++r) acc[mi][ni][r] = 0.0f;

  const short* Wa = wb + 4 * kWElems;
  const short* Wo = wb + 5 * kWElems;

  for (int k0 = 0; k0 < 1024; k0 += 32) {
    const short* Asrc = (k0 < 512) ? attn : cb;
    const short* Bsrc = (k0 < 512) ? Wa : Wo;
    const int ka = k0 & 511;
    const short* ga = Asrc + (size_t)(m0 + wave * 32 + srow) * kC + ka + schunk * 8;
    gload_lds16(ga,            &As[(wave * 32) * 32]);
    gload_lds16(ga + 16 * kC,  &As[(wave * 32 + 16) * 32]);
    const short* gb = Bsrc + (size_t)(n0 + wave * 16 + srow) * kC + ka + schunk * 8;
    gload_lds16(gb, &Bs[(wave * 16) * 32]);
    __syncthreads();

    bf16x8 af[4], bfr[2];
#pragma unroll
    for (int mi = 0; mi < 4; ++mi)
      af[mi] = *(const bf16x8*)(&As[(wm * 64 + mi * 16 + row) * 32 + quad * 8]);
#pragma unroll
    for (int ni = 0; ni < 2; ++ni)
      bfr[ni] = *(const bf16x8*)(&Bs[(wn * 32 + ni * 16 + row) * 32 + quad * 8]);
#pragma unroll
    for (int mi = 0; mi < 4; ++mi)
#pragma unroll
      for (int ni = 0; ni < 2; ++ni)
        acc[mi][ni] = __builtin_amdgcn_mfma_f32_16x16x32_bf16(
            af[mi], bfr[ni], acc[mi][ni], 0, 0, 0);
    __syncthreads();
  }

#pragma unroll
  for (int mi = 0; mi < 4; ++mi)
#pragma unroll
    for (int ni = 0; ni < 2; ++ni)
#pragma unroll
      for (int r = 0; r < 4; ++r) {
        const int gm = m0 + wm * 64 + mi * 16 + quad * 4 + r;
        const int gc = n0 + wn * 32 + ni * 16 + row;
        stf(out + (size_t)gm * kC + gc, acc[mi][ni][r]);
      }
}

__global__ __launch_bounds__(256, 4) void out_gemm(
    const short* __restrict__ attn, const short* __restrict__ cb,
    const short* __restrict__ wb, const int* __restrict__ flag, void* out) {
  if (*flag)
    out_body<short>(attn, cb, wb, (short*)out);
  else
    out_body<float>(attn, cb, wb, (float*)out);
}

extern "C" void kernel_launch(void* const* d_in, const int* in_sizes, int n_in,
                              void* d_out, int out_size, void* d_ws, size_t ws_size,
                              hipStream_t stream) {
  const void* x   = d_in[0];
  const void* Wq  = d_in[1];
  const void* Wk  = d_in[2];
  const void* Wv  = d_in[3];
  const void* Wa  = d_in[4];
  const void* Wc  = d_in[5];
  const void* dwk = d_in[6];
  const void* dwb = d_in[7];
  const void* Wco = d_in[8];

  short* ws = (short*)d_ws;
  const size_t E = (size_t)kBN * kC;
  int*   flag = (int*)ws;
  short* wb   = ws + 256;
  short* q    = wb + kWAll + kWExtra;
  short* k    = q + E;
  short* vT   = k + E;
  short* ci   = vT + E;
  short* cb   = ci + E;
  short* attn = ci;   // attn overwrites ci (consumed by dwconv first)
  short* xb   = cb;   // consumed by proj_gemm before dwconv writes cb

  detect_dtype<<<1, 64, 0, stream>>>((const unsigned*)x, flag);
  convert_weights<<<(kWAll / 8 + kWExtra + 255) / 256, 256, 0, stream>>>(
      Wq, Wk, Wv, Wc, Wa, Wco, dwk, dwb, flag, wb);
  convert_x<<<kBN * kC / (256 * 8), 256, 0, stream>>>(x, flag, xb);
  proj_gemm<<<1024, 256, 0, stream>>>(xb, wb, q, k, vT, ci);
  dwconv<<<(kBN * kC) / (256 * 8), 256, 0, stream>>>(ci, wb, cb);
  attn_flash<<<512, 256, 0, stream>>>(q, k, vT, attn);
  out_gemm<<<512, 256, 0, stream>>>(attn, cb, wb, flag, d_out);
}

// Round 9
// 245.950 us; speedup vs baseline: 1.2810x; 1.0859x over previous
//
#include <hip/hip_runtime.h>

typedef __attribute__((ext_vector_type(8))) short bf16x8;
typedef __attribute__((ext_vector_type(4))) float f32x4;

constexpr int kB = 2, kN = 4096, kC = 512, kNH = 8, kHD = 64;
constexpr int kBN = kB * kN;                 // 8192
constexpr int kWElems = 262144;              // 512*512
constexpr int kWAll = 6 * kWElems;           // 6 weight matrices
constexpr int kWExtra = 3584;                // dwk(1536) + dwb(512) + dwkT(1536)
constexpr float kQScale = 0.1803368801f;     // (1/8) * log2(e)

__device__ __forceinline__ short f2bf(float f) {
  union { float f; unsigned u; } v; v.f = f;
  unsigned r = v.u + 0x7fffu + ((v.u >> 16) & 1u);
  return (short)(r >> 16);
}
__device__ __forceinline__ float bf2f(short s) {
  union { unsigned u; float f; } v; v.u = ((unsigned)(unsigned short)s) << 16;
  return v.f;
}
__device__ __forceinline__ float exp2_(float x) {
#if __has_builtin(__builtin_amdgcn_exp2f)
  return __builtin_amdgcn_exp2f(x);
#else
  return exp2f(x);
#endif
}
// pack two f32 -> two bf16 (round-half-up) in one dword via v_perm
__device__ __forceinline__ unsigned pk2bf(float a, float b) {
  union { float f; unsigned u; } ua, ub; ua.f = a; ub.f = b;
#if __has_builtin(__builtin_amdgcn_perm)
  return __builtin_amdgcn_perm(ub.u + 0x8000u, ua.u + 0x8000u, 0x07060302u);
#else
  return ((ua.u + 0x8000u) >> 16) | (((ub.u + 0x8000u) >> 16) << 16);
#endif
}

__device__ __forceinline__ bf16x8 ld8(const short* p) { return *(const bf16x8*)p; }
__device__ __forceinline__ bf16x8 ld8(const float* p) {
  float4 a = *(const float4*)p;
  float4 b = *(const float4*)(p + 4);
  bf16x8 r;
  r[0] = f2bf(a.x); r[1] = f2bf(a.y); r[2] = f2bf(a.z); r[3] = f2bf(a.w);
  r[4] = f2bf(b.x); r[5] = f2bf(b.y); r[6] = f2bf(b.z); r[7] = f2bf(b.w);
  return r;
}
__device__ __forceinline__ void stf(short* p, float v) { *p = f2bf(v); }
__device__ __forceinline__ void stf(float* p, float v) { *p = v; }

// async 16B global->LDS (LDS dest wave-uniform base + 16*lane).
__device__ __forceinline__ void gload_lds16(const void* g, void* l) {
  __builtin_amdgcn_global_load_lds(
      (const __attribute__((address_space(1))) void*)g,
      (__attribute__((address_space(3))) void*)l, 16, 0, 0);
}

// K0: classify input dtype on-device.
__global__ void detect_dtype(const unsigned* __restrict__ x, int* __restrict__ flag) {
  const int lane = threadIdx.x & 63;
  unsigned w = x[lane];
  int e = (int)((w >> 7) & 0xffu);
  bool bf = (e >= 100 && e <= 140);
  unsigned long long m = __ballot(bf);
  if (lane == 0) *flag = (__popcll(m) >= 32) ? 1 : 0;
}

// K0b: weights AND x -> bf16 in one launch.
// dst layout: [Wq,Wk,Wv,Wc,Wa,Wco | dwk 1536 | dwb 512 | dwkT 3x512]; xb separate.
constexpr int kW8 = kWAll / 8;        // 196608
constexpr int kX8 = kBN * kC / 8;     // 524288
__global__ __launch_bounds__(256) void convert_all(
    const void* Wq, const void* Wk, const void* Wv, const void* Wc,
    const void* Wa, const void* Wco, const void* dwk, const void* dwb,
    const void* x, const int* __restrict__ flag, short* __restrict__ dst,
    short* __restrict__ xb) {
  const int gtid = blockIdx.x * 256 + threadIdx.x;
  const bool bf = (*flag != 0);
  if (gtid < kW8) {
    const int e = gtid * 8;
    const int t = e >> 18, off = e & (kWElems - 1);
    const void* src = (t == 0) ? Wq : (t == 1) ? Wk : (t == 2) ? Wv
                    : (t == 3) ? Wc : (t == 4) ? Wa : Wco;
    bf16x8 v = bf ? ld8((const short*)src + off) : ld8((const float*)src + off);
    *(bf16x8*)(dst + e) = v;
  } else if (gtid < kW8 + kWExtra) {
    const int eoff = gtid - kW8;
    if (eoff < 1536) {
      dst[kWAll + eoff] = bf ? ((const short*)dwk)[eoff]
                             : f2bf(((const float*)dwk)[eoff]);
    } else if (eoff < 2048) {
      const int i = eoff - 1536;
      dst[kWAll + 1536 + i] = bf ? ((const short*)dwb)[i]
                                 : f2bf(((const float*)dwb)[i]);
    } else {
      const int t2 = eoff - 2048;
      const int tap = t2 >> 9, c = t2 & 511;
      dst[kWAll + 2048 + t2] = bf ? ((const short*)dwk)[c * 3 + tap]
                                  : f2bf(((const float*)dwk)[c * 3 + tap]);
    }
  } else if (gtid < kW8 + kWExtra + kX8) {
    const int e = (gtid - kW8 - kWExtra) * 8;
    bf16x8 v = bf ? ld8((const short*)x + e) : ld8((const float*)x + e);
    *(bf16x8*)(xb + e) = v;
  }
}

// ---------------------------------------------------------------------------
// K1: fused input projection GEMM [8192x512] x [2048x512]^T.
// BK=64 (8 iterations), XOR-source-swizzled staging: LDS[m][ch] holds global
// chunk ch^(m&7) so fragment b128 reads are bank-uniform with no padding.
// ---------------------------------------------------------------------------
__global__ __launch_bounds__(256, 3) void proj_gemm(
    const short* __restrict__ xb, const short* __restrict__ wb,
    short* __restrict__ q, short* __restrict__ k, short* __restrict__ vT,
    short* __restrict__ ci) {
  __shared__ __align__(16) short As[128 * 64];  // 16 KB
  __shared__ __align__(16) short Bs[128 * 64];  // 16 KB
  const int t = threadIdx.x;
  const int wave = t >> 6, lane = t & 63;
  const int row = lane & 15, quad = lane >> 4;
  const int bn = blockIdx.x & 15;
  const int bm = blockIdx.x >> 4;
  const int m0 = bm * 128, n0 = bn * 128;
  const int wm = wave & 1, wn = wave >> 1;
  const int lrow = lane >> 3, lch = lane & 7;   // staging: 8 rows x 8 chunks

  f32x4 acc[4][4];
#pragma unroll
  for (int mi = 0; mi < 4; ++mi)
#pragma unroll
    for (int ni = 0; ni < 4; ++ni)
#pragma unroll
      for (int r = 0; r < 4; ++r) acc[mi][ni][r] = 0.0f;

  for (int k0 = 0; k0 < kC; k0 += 64) {
#pragma unroll
    for (int p = 0; p < 4; ++p) {
      const int m = wave * 32 + p * 8 + lrow;     // tile row this lane stages
      const int kch = lch ^ (m & 7);              // swizzled source chunk
      gload_lds16(xb + (size_t)(m0 + m) * kC + k0 + kch * 8,
                  &As[(wave * 32 + p * 8) * 64]);
      gload_lds16(wb + (size_t)(n0 + m) * kC + k0 + kch * 8,
                  &Bs[(wave * 32 + p * 8) * 64]);
    }
    __syncthreads();

#pragma unroll
    for (int kk2 = 0; kk2 < 2; ++kk2) {
      bf16x8 af[4], bfr[4];
#pragma unroll
      for (int mi = 0; mi < 4; ++mi) {
        const int m = wm * 64 + mi * 16 + row;
        const int ch = (kk2 * 4 + quad) ^ (m & 7);
        af[mi] = *(const bf16x8*)(&As[m * 64 + ch * 8]);
      }
#pragma unroll
      for (int ni = 0; ni < 4; ++ni) {
        const int n = wn * 64 + ni * 16 + row;
        const int ch = (kk2 * 4 + quad) ^ (n & 7);
        bfr[ni] = *(const bf16x8*)(&Bs[n * 64 + ch * 8]);
      }
#pragma unroll
      for (int mi = 0; mi < 4; ++mi)
#pragma unroll
        for (int ni = 0; ni < 4; ++ni)
          acc[mi][ni] = __builtin_amdgcn_mfma_f32_16x16x32_bf16(
              af[mi], bfr[ni], acc[mi][ni], 0, 0, 0);
    }
    __syncthreads();
  }

  const int gc0 = n0 + wn * 64;
  const int mat = gc0 >> 9;
  const float scale = (mat == 0) ? kQScale : 1.0f;
#pragma unroll
  for (int mi = 0; mi < 4; ++mi) {
#pragma unroll
    for (int ni = 0; ni < 4; ++ni) {
#pragma unroll
      for (int r = 0; r < 4; ++r) {
        const int gm = m0 + wm * 64 + mi * 16 + quad * 4 + r;
        const int c_ = ((gc0 + ni * 16) & 511) + row;
        const int b_ = gm >> 12;
        const int n_ = gm & (kN - 1);
        const short bv = f2bf(acc[mi][ni][r] * scale);
        if (mat == 3) {
          ci[(b_ * kN + n_) * kC + c_] = bv;
        } else {
          const int h = c_ >> 6, d = c_ & 63;
          const int bh = b_ * kNH + h;
          if (mat == 0)      q[(bh * kN + n_) * kHD + d] = bv;
          else if (mat == 1) k[(bh * kN + n_) * kHD + d] = bv;
          else               vT[(bh * kHD + d) * kN + n_] = bv;
        }
      }
    }
  }
}

// K2: depthwise conv, vectorized bf16x8 (uses dwkT + dwb from wb).
__global__ __launch_bounds__(256) void dwconv(
    const short* __restrict__ ci, const short* __restrict__ wb,
    short* __restrict__ cb) {
  const int e0 = (blockIdx.x * 256 + threadIdx.x) * 8;
  const int c0 = e0 & (kC - 1);
  const int bn = e0 >> 9;
  const int n_ = bn & (kN - 1);
  bf16x8 xc = ld8(ci + e0);
  bf16x8 xm, xp;
  if (n_ > 0) xm = ld8(ci + e0 - kC);
  else
#pragma unroll
    for (int i = 0; i < 8; ++i) xm[i] = 0;
  if (n_ < kN - 1) xp = ld8(ci + e0 + kC);
  else
#pragma unroll
    for (int i = 0; i < 8; ++i) xp[i] = 0;
  bf16x8 w0 = ld8(wb + kWAll + 2048 + c0);
  bf16x8 w1 = ld8(wb + kWAll + 2048 + 512 + c0);
  bf16x8 w2 = ld8(wb + kWAll + 2048 + 1024 + c0);
  bf16x8 bi = ld8(wb + kWAll + 1536 + c0);
  bf16x8 o;
#pragma unroll
  for (int i = 0; i < 8; ++i) {
    float a = bf2f(bi[i]) + bf2f(xm[i]) * bf2f(w0[i]) +
              bf2f(xc[i]) * bf2f(w1[i]) + bf2f(xp[i]) * bf2f(w2[i]);
    o[i] = f2bf(a);
  }
  *(bf16x8*)(cb + e0) = o;
}

// ---------------------------------------------------------------------------
// K3: flash attention v5.
//  - K LDS [64][72] double-buffered (bank-uniform b128 reads/writes).
//  - V LDS double-buffered in PERMUTED layout: VbS[d][p], p = c*32+quad*8+j
//    holding V[c*32+(j>>2)*16+quad*4+(j&3)][d] -> PV A-frag is ONE contiguous
//    bank-uniform ds_read_b128 (was 2 scattered b64s = the conflict source).
//    Staging: each global 16B chunk splits into two b64 writes at base1/base1+8.
//  - P^T stays in registers (R8 trick), packed via v_perm round-half-up.
//  - ONE barrier per kt (both tiles double-buffered).
// ---------------------------------------------------------------------------
__global__ __launch_bounds__(256, 3) void attn_flash(
    const short* __restrict__ q, const short* __restrict__ k,
    const short* __restrict__ vT, short* __restrict__ attn) {
  __shared__ __align__(16) short Kb[2][64 * 72];    // 2 x 9216 B
  __shared__ __align__(16) short VbS[2][64 * 72];   // 2 x 9216 B
  const int t = threadIdx.x;
  const int wave = t >> 6;
  const int lane = t & 63;
  const int row = lane & 15;
  const int quad = lane >> 4;

  const int slot = blockIdx.x & 7;
  const int inner = blockIdx.x >> 3;
  const int bh = slot * 2 + (inner & 1);
  const int q0 = (inner >> 1) * 128 + wave * 32;

  const short* qbase = q + (bh * kN + q0) * kHD;
  const short* kbase = k + bh * kN * kHD;
  const short* vbase = vT + bh * kHD * kN;

  bf16x8 qb[2][2];
#pragma unroll
  for (int g = 0; g < 2; ++g) {
    qb[g][0] = *(const bf16x8*)(qbase + (g * 16 + row) * kHD + quad * 8);
    qb[g][1] = *(const bf16x8*)(qbase + (g * 16 + row) * kHD + 32 + quad * 8);
  }

  f32x4 o[2][4];   // O^T accumulators
#pragma unroll
  for (int g = 0; g < 2; ++g)
#pragma unroll
    for (int j = 0; j < 4; ++j)
#pragma unroll
      for (int r = 0; r < 4; ++r) o[g][j][r] = 0.0f;
  float l_[2] = {0.0f, 0.0f};

  // staging geometry: chunks i0,i1 per thread; sr = row, sc = chunk.
  const int i0 = t, i1 = t + 256;
  const int sr0 = i0 >> 3, sc0 = i0 & 7;
  const int sr1 = i1 >> 3, sc1 = i1 & 7;
  // V permuted write bases: tt = sc&3 -> base1 = (sc>>2)*32 + (tt&1)*16 + (tt&2)*2
  const int vb0 = (sc0 >> 2) * 32 + (sc0 & 1) * 16 + (sc0 & 2) * 2;
  const int vb1 = (sc1 >> 2) * 32 + (sc1 & 1) * 16 + (sc1 & 2) * 2;

  auto stage_v = [&](int buf, bf16x8 v0, bf16x8 v1) {
    *(short4*)(&VbS[buf][sr0 * 72 + vb0]) =
        make_short4(v0[0], v0[1], v0[2], v0[3]);
    *(short4*)(&VbS[buf][sr0 * 72 + vb0 + 8]) =
        make_short4(v0[4], v0[5], v0[6], v0[7]);
    *(short4*)(&VbS[buf][sr1 * 72 + vb1]) =
        make_short4(v1[0], v1[1], v1[2], v1[3]);
    *(short4*)(&VbS[buf][sr1 * 72 + vb1 + 8]) =
        make_short4(v1[4], v1[5], v1[6], v1[7]);
  };

  { // prologue: K0, V0 -> buffer 0
    bf16x8 ka = *(const bf16x8*)(kbase + i0 * 8);
    bf16x8 kb2 = *(const bf16x8*)(kbase + i1 * 8);
    *(bf16x8*)(&Kb[0][sr0 * 72 + sc0 * 8]) = ka;
    *(bf16x8*)(&Kb[0][sr1 * 72 + sc1 * 8]) = kb2;
    bf16x8 v0 = *(const bf16x8*)(vbase + sr0 * kN + sc0 * 8);
    bf16x8 v1 = *(const bf16x8*)(vbase + sr1 * kN + sc1 * 8);
    stage_v(0, v0, v1);
  }
  __syncthreads();

  for (int kt = 0; kt < kN / 64; ++kt) {
    const int cur = kt & 1;
    const bool more = (kt < kN / 64 - 1);
    bf16x8 kn0, kn1, vn0, vn1;
    if (more) {
      kn0 = *(const bf16x8*)(kbase + (kt + 1) * 4096 + i0 * 8);
      kn1 = *(const bf16x8*)(kbase + (kt + 1) * 4096 + i1 * 8);
      vn0 = *(const bf16x8*)(vbase + sr0 * kN + (kt + 1) * 64 + sc0 * 8);
      vn1 = *(const bf16x8*)(vbase + sr1 * kN + (kt + 1) * 64 + sc1 * 8);
    }

    // ---- QK: S^T strips ----
    f32x4 s[2][4];
#pragma unroll
    for (int g = 0; g < 2; ++g)
#pragma unroll
      for (int jk = 0; jk < 4; ++jk)
#pragma unroll
        for (int r = 0; r < 4; ++r) s[g][jk][r] = 0.0f;
#pragma unroll
    for (int jk = 0; jk < 4; ++jk) {
      const short* kr = &Kb[cur][(jk * 16 + row) * 72 + quad * 8];
      bf16x8 a0 = *(const bf16x8*)kr;
      bf16x8 a1 = *(const bf16x8*)(kr + 32);
#pragma unroll
      for (int g = 0; g < 2; ++g) {
        s[g][jk] = __builtin_amdgcn_mfma_f32_16x16x32_bf16(a0, qb[g][0], s[g][jk], 0, 0, 0);
        s[g][jk] = __builtin_amdgcn_mfma_f32_16x16x32_bf16(a1, qb[g][1], s[g][jk], 0, 0, 0);
      }
    }

    // ---- softmax (fixed ref, exp2 domain) + in-register P^T B-frags ----
    bf16x8 pb[2][2];
#pragma unroll
    for (int g = 0; g < 2; ++g) {
      float rs = 0.0f;
#pragma unroll
      for (int jk = 0; jk < 4; ++jk)
#pragma unroll
        for (int r = 0; r < 4; ++r) {
          float p = exp2_(s[g][jk][r]);
          s[g][jk][r] = p;
          rs += p;
        }
      l_[g] += rs;
#pragma unroll
      for (int c = 0; c < 2; ++c) {
        union { unsigned u[4]; bf16x8 v; } pu;
        pu.u[0] = pk2bf(s[g][2 * c][0], s[g][2 * c][1]);
        pu.u[1] = pk2bf(s[g][2 * c][2], s[g][2 * c][3]);
        pu.u[2] = pk2bf(s[g][2 * c + 1][0], s[g][2 * c + 1][1]);
        pu.u[3] = pk2bf(s[g][2 * c + 1][2], s[g][2 * c + 1][3]);
        pb[g][c] = pu.v;
      }
    }

    // ---- PV: A = one b128 from permuted V, B = pb regs ----
#pragma unroll
    for (int jd = 0; jd < 4; ++jd) {
      const short* vb = &VbS[cur][(jd * 16 + row) * 72 + quad * 8];
#pragma unroll
      for (int c = 0; c < 2; ++c) {
        bf16x8 av = *(const bf16x8*)(vb + c * 32);
#pragma unroll
        for (int g = 0; g < 2; ++g)
          o[g][jd] = __builtin_amdgcn_mfma_f32_16x16x32_bf16(
              av, pb[g][c], o[g][jd], 0, 0, 0);
      }
    }

    // ---- stage next tiles into the other buffer; one barrier ----
    if (more) {
      *(bf16x8*)(&Kb[1 - cur][sr0 * 72 + sc0 * 8]) = kn0;
      *(bf16x8*)(&Kb[1 - cur][sr1 * 72 + sc1 * 8]) = kn1;
      stage_v(1 - cur, vn0, vn1);
    }
    __syncthreads();
  }

  // ---- finalize: O^T -> attn[B][N][C], packed 8B stores ----
  const int b_ = bh >> 3, h = bh & 7;
#pragma unroll
  for (int g = 0; g < 2; ++g) {
    float lt = l_[g];
    lt += __shfl_xor(lt, 16);
    lt += __shfl_xor(lt, 32);
    const float linv = 1.0f / lt;
    const int n_ = q0 + g * 16 + row;
    short* ob = attn + (b_ * kN + n_) * kC + h * kHD + quad * 4;
#pragma unroll
    for (int jd = 0; jd < 4; ++jd) {
      short4 st = make_short4(f2bf(o[g][jd][0] * linv), f2bf(o[g][jd][1] * linv),
                              f2bf(o[g][jd][2] * linv), f2bf(o[g][jd][3] * linv));
      *(short4*)(ob + jd * 16) = st;
    }
  }
}

// ---------------------------------------------------------------------------
// K4: out = [attn|cb] @ [Wa|Wo]^T, GEMM M=8192 N=512 K=1024 (K-concat),
// BK=64, XOR-source-swizzled staging.
// ---------------------------------------------------------------------------
template <typename TO>
__device__ __forceinline__ void out_body(
    const short* __restrict__ attn, const short* __restrict__ cb,
    const short* __restrict__ wb, TO* __restrict__ out) {
  __shared__ __align__(16) short As[128 * 64];  // 16 KB
  __shared__ __align__(16) short Bs[64 * 64];   //  8 KB
  const int t = threadIdx.x;
  const int wave = t >> 6, lane = t & 63;
  const int row = lane & 15, quad = lane >> 4;
  const int bn = blockIdx.x & 7;
  const int bm = blockIdx.x >> 3;
  const int m0 = bm * 128, n0 = bn * 64;
  const int wm = wave & 1, wn = wave >> 1;
  const int lrow = lane >> 3, lch = lane & 7;

  f32x4 acc[4][2];
#pragma unroll
  for (int mi = 0; mi < 4; ++mi)
#pragma unroll
    for (int ni = 0; ni < 2; ++ni)
#pragma unroll
      for (int r = 0; r < 4; ++r) acc[mi][ni][r] = 0.0f;

  const short* Wa = wb + 4 * kWElems;
  const short* Wo = wb + 5 * kWElems;

  for (int k0 = 0; k0 < 1024; k0 += 64) {
    const short* Asrc = (k0 < 512) ? attn : cb;
    const short* Bsrc = (k0 < 512) ? Wa : Wo;
    const int ka = k0 & 511;
#pragma unroll
    for (int p = 0; p < 4; ++p) {
      const int m = wave * 32 + p * 8 + lrow;
      const int kch = lch ^ (m & 7);
      gload_lds16(Asrc + (size_t)(m0 + m) * kC + ka + kch * 8,
                  &As[(wave * 32 + p * 8) * 64]);
    }
#pragma unroll
    for (int p = 0; p < 2; ++p) {
      const int n = wave * 16 + p * 8 + lrow;
      const int kch = lch ^ (n & 7);
      gload_lds16(Bsrc + (size_t)(n0 + n) * kC + ka + kch * 8,
                  &Bs[(wave * 16 + p * 8) * 64]);
    }
    __syncthreads();

#pragma unroll
    for (int kk2 = 0; kk2 < 2; ++kk2) {
      bf16x8 af[4], bfr[2];
#pragma unroll
      for (int mi = 0; mi < 4; ++mi) {
        const int m = wm * 64 + mi * 16 + row;
        const int ch = (kk2 * 4 + quad) ^ (m & 7);
        af[mi] = *(const bf16x8*)(&As[m * 64 + ch * 8]);
      }
#pragma unroll
      for (int ni = 0; ni < 2; ++ni) {
        const int n = wn * 32 + ni * 16 + row;
        const int ch = (kk2 * 4 + quad) ^ (n & 7);
        bfr[ni] = *(const bf16x8*)(&Bs[n * 64 + ch * 8]);
      }
#pragma unroll
      for (int mi = 0; mi < 4; ++mi)
#pragma unroll
        for (int ni = 0; ni < 2; ++ni)
          acc[mi][ni] = __builtin_amdgcn_mfma_f32_16x16x32_bf16(
              af[mi], bfr[ni], acc[mi][ni], 0, 0, 0);
    }
    __syncthreads();
  }

#pragma unroll
  for (int mi = 0; mi < 4; ++mi)
#pragma unroll
    for (int ni = 0; ni < 2; ++ni)
#pragma unroll
      for (int r = 0; r < 4; ++r) {
        const int gm = m0 + wm * 64 + mi * 16 + quad * 4 + r;
        const int gc = n0 + wn * 32 + ni * 16 + row;
        stf(out + (size_t)gm * kC + gc, acc[mi][ni][r]);
      }
}

__global__ __launch_bounds__(256, 4) void out_gemm(
    const short* __restrict__ attn, const short* __restrict__ cb,
    const short* __restrict__ wb, const int* __restrict__ flag, void* out) {
  if (*flag)
    out_body<short>(attn, cb, wb, (short*)out);
  else
    out_body<float>(attn, cb, wb, (float*)out);
}

extern "C" void kernel_launch(void* const* d_in, const int* in_sizes, int n_in,
                              void* d_out, int out_size, void* d_ws, size_t ws_size,
                              hipStream_t stream) {
  const void* x   = d_in[0];
  const void* Wq  = d_in[1];
  const void* Wk  = d_in[2];
  const void* Wv  = d_in[3];
  const void* Wa  = d_in[4];
  const void* Wc  = d_in[5];
  const void* dwk = d_in[6];
  const void* dwb = d_in[7];
  const void* Wco = d_in[8];

  short* ws = (short*)d_ws;
  const size_t E = (size_t)kBN * kC;
  int*   flag = (int*)ws;
  short* wb   = ws + 256;
  short* q    = wb + kWAll + kWExtra;
  short* k    = q + E;
  short* vT   = k + E;
  short* ci   = vT + E;
  short* cb   = ci + E;
  short* attn = ci;   // attn overwrites ci (consumed by dwconv first)
  short* xb   = cb;   // consumed by proj_gemm before dwconv writes cb

  detect_dtype<<<1, 64, 0, stream>>>((const unsigned*)x, flag);
  const int cvt_threads = kW8 + kWExtra + kX8;
  convert_all<<<(cvt_threads + 255) / 256, 256, 0, stream>>>(
      Wq, Wk, Wv, Wc, Wa, Wco, dwk, dwb, x, flag, wb, xb);
  proj_gemm<<<1024, 256, 0, stream>>>(xb, wb, q, k, vT, ci);
  dwconv<<<(kBN * kC) / (256 * 8), 256, 0, stream>>>(ci, wb, cb);
  attn_flash<<<512, 256, 0, stream>>>(q, k, vT, attn);
  out_gemm<<<512, 256, 0, stream>>>(attn, cb, wb, flag, d_out);
}